// Round 11
// baseline (218.659 us; speedup 1.0000x reference)
//
#include <hip/hip_runtime.h>

#define NB 16
#define S_TOK 577
#define SP 576
#define DIM 768
#define NC 256
#define NCLS 1000
#define TK 16
#define HCH 6
#define HCHS 96    // 576/6
#define NSB 9      // s-blocks of 64
#define NCAND (NSB * TK)  // 144

typedef __attribute__((ext_vector_type(8))) __bf16 bf16x8;
typedef __attribute__((ext_vector_type(4))) float f32x4;

// Split one 8-float chunk into hi/lo bf16 (RNE both steps).
__device__ __forceinline__ void cvt_split(const float4 a, const float4 b,
                                          bf16x8& hi, bf16x8& lo) {
  float v[8] = {a.x, a.y, a.z, a.w, b.x, b.y, b.z, b.w};
#pragma unroll
  for (int i = 0; i < 8; i++) {
    __bf16 h = (__bf16)v[i];
    hi[i] = h;
    lo[i] = (__bf16)(v[i] - (float)h);
  }
}

// Read one 16B MFMA fragment (row r, k-chunk kc) from a swizzled LDS tile.
__device__ __forceinline__ bf16x8 frag_ld(const char* base, int r, int kc) {
  return *(const bf16x8*)(base + ((r * 4 + (kc ^ (r & 3))) << 4));
}

// ---------------- Kernel A: 64c x 64s GEMM tile + fused per-segment top-16 --
// R4-validated LDS-staged 3-pass bf16 MFMA (fused f32->hi/lo convert).
// Epilogue: acc -> tkbuf[64][65] -> per-wave top-16-of-64 -> cand/candi.
// Blocks (0, 0, b) also zero W for the downstream merge scatter.
__global__ __launch_bounds__(256) void gemm_topk64(const float* __restrict__ q,
                                                   const float* __restrict__ cw,
                                                   float* __restrict__ cand,
                                                   int* __restrict__ candi,
                                                   float* __restrict__ W) {
  const int b = blockIdx.z;
  const int sb = blockIdx.x;       // 0..8
  const int s0 = sb * 64;
  const int c0 = blockIdx.y * 64;  // 0..192
  __shared__ __align__(16) char sAH[4096], sAL[4096], sBH[4096], sBL[4096];
  __shared__ float tkbuf[64][65];  // +1 pad: conflict-free epilogue

  if (blockIdx.x == 0 && blockIdx.y == 0) {
    for (int i = threadIdx.x; i < SP; i += 256) W[b * SP + i] = 0.f;
  }

  const int tid = threadIdx.x;
  const int lane = tid & 63;
  const int wid = tid >> 6;
  const int wc = (wid >> 1) << 5;  // wave c-offset (0/32)
  const int wsv = (wid & 1) << 5;  // wave s-offset (0/32)
  const int fr = lane & 15;
  const int kq = lane >> 4;  // k-chunk 0..3

  // staging coords: thread -> (row 0..63, 8-float chunk 0..3), swizzled slot
  const int r = tid >> 2;
  const int ck = tid & 3;
  const int wslot = (r * 4 + (ck ^ (r & 3))) << 4;

  const float* qb = q + ((size_t)b * S_TOK + 1) * DIM;
  const float* arow = cw + (size_t)(c0 + r) * DIM + ck * 8;
  const float* brow = qb + (size_t)(s0 + r) * DIM + ck * 8;

  f32x4 zero = {0.f, 0.f, 0.f, 0.f};
  f32x4 acc[2][2];
#pragma unroll
  for (int i = 0; i < 2; i++)
#pragma unroll
    for (int j = 0; j < 2; j++) acc[i][j] = zero;

  for (int k0 = 0; k0 < DIM; k0 += 32) {
    float4 a0 = *(const float4*)(arow + k0);
    float4 a1 = *(const float4*)(arow + k0 + 4);
    float4 b0v = *(const float4*)(brow + k0);
    float4 b1v = *(const float4*)(brow + k0 + 4);
    __syncthreads();  // previous iter's fragment readers done
    bf16x8 h, l;
    cvt_split(a0, a1, h, l);
    *(bf16x8*)(sAH + wslot) = h;
    *(bf16x8*)(sAL + wslot) = l;
    cvt_split(b0v, b1v, h, l);
    *(bf16x8*)(sBH + wslot) = h;
    *(bf16x8*)(sBL + wslot) = l;
    __syncthreads();
    bf16x8 a0h = frag_ld(sAH, wc + fr, kq);
    bf16x8 a0l = frag_ld(sAL, wc + fr, kq);
    bf16x8 a1h = frag_ld(sAH, wc + 16 + fr, kq);
    bf16x8 a1l = frag_ld(sAL, wc + 16 + fr, kq);
    bf16x8 b0h = frag_ld(sBH, wsv + fr, kq);
    bf16x8 b0l = frag_ld(sBL, wsv + fr, kq);
    bf16x8 b1h = frag_ld(sBH, wsv + 16 + fr, kq);
    bf16x8 b1l = frag_ld(sBL, wsv + 16 + fr, kq);
#define MF(A, B, C) C = __builtin_amdgcn_mfma_f32_16x16x32_bf16(A, B, C, 0, 0, 0)
    MF(a0h, b0h, acc[0][0]); MF(a0h, b0l, acc[0][0]); MF(a0l, b0h, acc[0][0]);
    MF(a0h, b1h, acc[0][1]); MF(a0h, b1l, acc[0][1]); MF(a0l, b1h, acc[0][1]);
    MF(a1h, b0h, acc[1][0]); MF(a1h, b0l, acc[1][0]); MF(a1l, b0h, acc[1][0]);
    MF(a1h, b1h, acc[1][1]); MF(a1h, b1l, acc[1][1]); MF(a1l, b1h, acc[1][1]);
#undef MF
  }

  // ---- epilogue: acc -> tkbuf (C layout: row(c)=(lane>>4)*4+reg, col(s)) ---
  __syncthreads();  // all LDS fragment reads done before repurposing
#pragma unroll
  for (int i = 0; i < 2; i++)
#pragma unroll
    for (int j = 0; j < 2; j++)
#pragma unroll
      for (int rr = 0; rr < 4; rr++)
        tkbuf[wc + i * 16 + kq * 4 + rr][wsv + j * 16 + fr] = acc[i][j][rr];
  __syncthreads();

  // ---- per-wave top-16-of-64 for rows wid*16 .. wid*16+15 -----------------
  for (int rr2 = 0; rr2 < 16; ++rr2) {
    const int row = wid * 16 + rr2;
    float v = tkbuf[row][lane];
    const size_t obase = ((size_t)(b * NC + c0 + row)) * NCAND + sb * TK;
    for (int t = 0; t < TK; t++) {
      float bv = v;
      int bs = lane;
#pragma unroll
      for (int off = 32; off >= 1; off >>= 1) {
        float ov = __shfl_xor(bv, off);
        int os = __shfl_xor(bs, off);
        if (ov > bv || (ov == bv && os < bs)) { bv = ov; bs = os; }
      }
      if (lane == 0) {
        cand[obase + t] = bv;
        candi[obase + t] = s0 + bs;
      }
      if (lane == bs) v = -1e30f;  // retire winner
    }
  }
}

// ---------------- Kernel B: merge 144 candidates -> top-16, softmax, scatter
__global__ __launch_bounds__(256) void merge_scatter(const float* __restrict__ cand,
                                                     const int* __restrict__ candi,
                                                     float* __restrict__ W) {
  const int lane = threadIdx.x & 63;
  const int wid = threadIdx.x >> 6;
  const int rc = blockIdx.x * 4 + wid;  // 0..4095
  const int b = rc >> 8;
  float v[3];
  int vi[3];
#pragma unroll
  for (int j = 0; j < 3; j++) {
    const int idx = lane + 64 * j;
    if (idx < NCAND) {
      v[j] = cand[(size_t)rc * NCAND + idx];
      vi[j] = candi[(size_t)rc * NCAND + idx];
    } else {
      v[j] = -1e30f;
      vi[j] = 0x7fffffff;
    }
  }
  float vals[TK];
  int idxs[TK];
#pragma unroll
  for (int t = 0; t < TK; t++) {
    float bv = v[0];
    int bi = vi[0];
#pragma unroll
    for (int j = 1; j < 3; j++)
      if (v[j] > bv || (v[j] == bv && vi[j] < bi)) { bv = v[j]; bi = vi[j]; }
#pragma unroll
    for (int off = 32; off >= 1; off >>= 1) {
      float ov = __shfl_xor(bv, off);
      int oi = __shfl_xor(bi, off);
      if (ov > bv || (ov == bv && oi < bi)) { bv = ov; bi = oi; }
    }
    vals[t] = bv;
    idxs[t] = bi;
#pragma unroll
    for (int j = 0; j < 3; j++)
      if (vi[j] == bi) v[j] = -1e30f;  // s-index unique -> exact retire
  }
  float m = vals[0];
  float sum = 0.f;
#pragma unroll
  for (int t = 0; t < TK; t++) sum += expf(vals[t] - m);
  if (lane == 0) {
    const float inv = 1.f / (sum * (float)NC);
#pragma unroll
    for (int t = 0; t < TK; t++)
      atomicAdd(&W[b * SP + idxs[t]], expf(vals[t] - m) * inv);
  }
}

// ---------------- Kernel C: hpart[ch,b,d] = sum_{s in chunk} W*q ------------
__global__ __launch_bounds__(256) void h_partial(const float* __restrict__ q,
                                                 const float* __restrict__ W,
                                                 float* __restrict__ hpart) {
  const int b = blockIdx.y;
  const int ch = blockIdx.z;
  const int d = blockIdx.x * 256 + threadIdx.x;
  __shared__ float Ws[HCHS];
  if (threadIdx.x < HCHS) Ws[threadIdx.x] = W[b * SP + ch * HCHS + threadIdx.x];
  __syncthreads();
  const float* qb = q + ((size_t)b * S_TOK + 1 + ch * HCHS) * DIM + d;
  float acc = 0.f;
#pragma unroll 8
  for (int s = 0; s < HCHS; s++) acc = fmaf(Ws[s], qb[(size_t)s * DIM], acc);
  hpart[((size_t)ch * NB + b) * DIM + d] = acc;
}

// ---------------- Kernel D: y = relu(sum_ch hpart) @ cls_w^T + cls_b --------
__global__ __launch_bounds__(256) void cls_head(const float* __restrict__ hp,
                                                const float* __restrict__ cw,
                                                const float* __restrict__ cb,
                                                float* __restrict__ y) {
  __shared__ float hs[NB * DIM];
  for (int i = threadIdx.x; i < NB * DIM; i += 256) {
    float s = 0.f;
#pragma unroll
    for (int ch = 0; ch < HCH; ch++) s += hp[(size_t)ch * NB * DIM + i];
    hs[i] = fmaxf(s, 0.f);
  }
  __syncthreads();
  const int lane = threadIdx.x & 63;
  const int n = blockIdx.x * 4 + (threadIdx.x >> 6);
  float wr[12];
#pragma unroll
  for (int j = 0; j < 12; j++) wr[j] = cw[(size_t)n * DIM + lane + 64 * j];
  const float bias = cb[n];
  for (int bb = 0; bb < NB; bb++) {
    float dot = 0.f;
#pragma unroll
    for (int j = 0; j < 12; j++)
      dot = fmaf(wr[j], hs[bb * DIM + lane + 64 * j], dot);
#pragma unroll
    for (int off = 32; off >= 1; off >>= 1) dot += __shfl_xor(dot, off);
    if (lane == 0) y[bb * NCLS + n] = dot + bias;
  }
}

extern "C" void kernel_launch(void* const* d_in, const int* in_sizes, int n_in,
                              void* d_out, int out_size, void* d_ws, size_t ws_size,
                              hipStream_t stream) {
  const float* q = (const float*)d_in[0];
  const float* cw = (const float*)d_in[1];
  const float* clsw = (const float*)d_in[2];
  const float* clsb = (const float*)d_in[3];
  float* out = (float*)d_out;

  float* W = (float*)d_ws;                           // NB*SP
  float* hpart = W + (size_t)NB * SP;                // HCH*NB*DIM
  float* cand = hpart + (size_t)HCH * NB * DIM;      // NB*NC*NCAND f32
  int* candi = (int*)(cand + (size_t)NB * NC * NCAND);

  gemm_topk64<<<dim3(NSB, 4, NB), 256, 0, stream>>>(q, cw, cand, candi, W);
  merge_scatter<<<(NB * NC) / 4, 256, 0, stream>>>(cand, candi, W);
  h_partial<<<dim3(3, NB, HCH), 256, 0, stream>>>(q, W, hpart);
  cls_head<<<NCLS / 4, 256, 0, stream>>>(hpart, clsw, clsb, out);
}

// Round 12
// 105.768 us; speedup vs baseline: 2.0673x; 2.0673x over previous
//
#include <hip/hip_runtime.h>

#define NB 16
#define S_TOK 577
#define SP 576
#define DIM 768
#define NC 256
#define NCLS 1000
#define TK 16
#define NCAND 24
#define HCH 6
#define HCHS 96  // 576/6

typedef __attribute__((ext_vector_type(8))) __bf16 bf16x8;
typedef __attribute__((ext_vector_type(4))) float f32x4;

// Read one 16B MFMA fragment (row r, k-chunk kc) from a swizzled LDS tile.
__device__ __forceinline__ bf16x8 frag_ld(const char* base, int r, int kc) {
  return *(const bf16x8*)(base + ((r * 4 + (kc ^ (r & 3))) << 4));
}

// Ordered-uint key: float-monotone high bits, (1023-s) tie-break in low 10.
__device__ __forceinline__ unsigned okey(float f, int s) {
  unsigned u = __float_as_uint(f);
  u = (u & 0x80000000u) ? ~u : (u | 0x80000000u);
  return (u & ~1023u) | (1023u - (unsigned)s);
}

// ---------------- Kernel A: qk[b,c,s] approx, single-pass bf16 MFMA --------
// 64c x 64s tile (R4/R11-validated core, hi-only). Blocks (0,0,b) zero W.
__global__ __launch_bounds__(256) void qk_gemm_bf16s(const float* __restrict__ q,
                                                     const float* __restrict__ cw,
                                                     float* __restrict__ qk,
                                                     float* __restrict__ W) {
  const int b = blockIdx.z;
  const int s0 = blockIdx.x * 64;
  const int c0 = blockIdx.y * 64;
  __shared__ __align__(16) char sAH[4096], sBH[4096];

  if (blockIdx.x == 0 && blockIdx.y == 0) {
    for (int i = threadIdx.x; i < SP; i += 256) W[b * SP + i] = 0.f;
  }

  const int tid = threadIdx.x;
  const int lane = tid & 63;
  const int wid = tid >> 6;
  const int wc = (wid >> 1) << 5;  // wave c-offset (0/32)
  const int wsv = (wid & 1) << 5;  // wave s-offset (0/32)
  const int fr = lane & 15;
  const int kq = lane >> 4;  // k-chunk 0..3

  const int r = tid >> 2;
  const int ck = tid & 3;
  const int wslot = (r * 4 + (ck ^ (r & 3))) << 4;

  const float* qb = q + ((size_t)b * S_TOK + 1) * DIM;
  const float* arow = cw + (size_t)(c0 + r) * DIM + ck * 8;
  const float* brow = qb + (size_t)(s0 + r) * DIM + ck * 8;

  f32x4 zero = {0.f, 0.f, 0.f, 0.f};
  f32x4 acc[2][2];
#pragma unroll
  for (int i = 0; i < 2; i++)
#pragma unroll
    for (int j = 0; j < 2; j++) acc[i][j] = zero;

  for (int k0 = 0; k0 < DIM; k0 += 32) {
    float4 a0 = *(const float4*)(arow + k0);
    float4 a1 = *(const float4*)(arow + k0 + 4);
    float4 b0v = *(const float4*)(brow + k0);
    float4 b1v = *(const float4*)(brow + k0 + 4);
    __syncthreads();  // previous iter's fragment readers done
    {
      float va[8] = {a0.x, a0.y, a0.z, a0.w, a1.x, a1.y, a1.z, a1.w};
      float vb[8] = {b0v.x, b0v.y, b0v.z, b0v.w, b1v.x, b1v.y, b1v.z, b1v.w};
      bf16x8 ha, hb;
#pragma unroll
      for (int i = 0; i < 8; i++) {
        ha[i] = (__bf16)va[i];
        hb[i] = (__bf16)vb[i];
      }
      *(bf16x8*)(sAH + wslot) = ha;
      *(bf16x8*)(sBH + wslot) = hb;
    }
    __syncthreads();
    bf16x8 a0h = frag_ld(sAH, wc + fr, kq);
    bf16x8 a1h = frag_ld(sAH, wc + 16 + fr, kq);
    bf16x8 b0h = frag_ld(sBH, wsv + fr, kq);
    bf16x8 b1h = frag_ld(sBH, wsv + 16 + fr, kq);
#define MF(A, B, C) C = __builtin_amdgcn_mfma_f32_16x16x32_bf16(A, B, C, 0, 0, 0)
    MF(a0h, b0h, acc[0][0]);
    MF(a0h, b1h, acc[0][1]);
    MF(a1h, b0h, acc[1][0]);
    MF(a1h, b1h, acc[1][1]);
#undef MF
  }
  // C/D layout (m89-verified): col(s) = lane&15, row(c) = (lane>>4)*4 + reg
  float* obase = qk + (size_t)b * NC * SP;
#pragma unroll
  for (int i = 0; i < 2; i++)
#pragma unroll
    for (int j = 0; j < 2; j++)
#pragma unroll
      for (int rr = 0; rr < 4; rr++) {
        const int row = c0 + wc + i * 16 + kq * 4 + rr;
        const int col = s0 + wsv + j * 16 + fr;
        obase[(size_t)row * SP + col] = acc[i][j][rr];
      }
}

// ---------------- Kernel B: top-24 approx -> exact f32 rescore -> top-16 ---
// 1024 blocks x 4 waves; wave owns one (b,c) row end-to-end.
__global__ __launch_bounds__(256) void topk_rescore(const float* __restrict__ q,
                                                    const float* __restrict__ cw,
                                                    const float* __restrict__ qk,
                                                    float* __restrict__ W) {
  __shared__ int sIdx[4][NCAND];
  __shared__ float sVal[4][NCAND];
  const int lane = threadIdx.x & 63;
  const int wid = threadIdx.x >> 6;
  const int rc = blockIdx.x * 4 + wid;  // 0..4095
  const int b = rc >> 8;
  const int c = rc & 255;

  // --- approx top-24 via packed keys (1 bpermute per level) ---
  const float* rowp = qk + (size_t)rc * SP;
  unsigned k[9];
#pragma unroll
  for (int j = 0; j < 9; j++) k[j] = okey(rowp[lane + 64 * j], lane + 64 * j);

  for (int t = 0; t < NCAND; t++) {
    unsigned bk = k[0];
#pragma unroll
    for (int j = 1; j < 9; j++) bk = max(bk, k[j]);
#pragma unroll
    for (int off = 32; off >= 1; off >>= 1)
      bk = max(bk, (unsigned)__shfl_xor((int)bk, off));
    const int s = 1023 - (int)(bk & 1023u);
    const int cj = s >> 6, cl = s & 63;
#pragma unroll
    for (int j = 0; j < 9; j++)
      if (j == cj && cl == lane) k[j] = 0u;  // retire winner (static idx)
    if (lane == 0) sIdx[wid][t] = s;
  }
  __syncthreads();

  // --- exact f32 rescore of the 24 candidates ---
  const float* qrow = q + ((size_t)b * S_TOK + 1) * DIM + lane;
  const float* crow = cw + (size_t)c * DIM + lane;
  float cr[12];
#pragma unroll
  for (int m = 0; m < 12; m++) cr[m] = crow[64 * m];
  for (int t = 0; t < NCAND; t++) {
    const int s = sIdx[wid][t];
    const float* qp_ = qrow + (size_t)s * DIM;
    float d = 0.f;
#pragma unroll
    for (int m = 0; m < 12; m++) d = fmaf(qp_[64 * m], cr[m], d);
#pragma unroll
    for (int off = 32; off >= 1; off >>= 1) d += __shfl_xor(d, off);
    if (lane == 0) sVal[wid][t] = d;
  }
  __syncthreads();

  // --- exact top-16-of-24 (jax tie-break: lower s first), softmax, scatter --
  float cv = -1e30f;
  int ci = 0x7fffffff;
  if (lane < NCAND) {
    cv = sVal[wid][lane];
    ci = sIdx[wid][lane];
  }
  float vals[TK];
  int idxs[TK];
#pragma unroll
  for (int t = 0; t < TK; t++) {
    float bv = cv;
    int bi = ci;
#pragma unroll
    for (int off = 32; off >= 1; off >>= 1) {
      float ov = __shfl_xor(bv, off);
      int oi = __shfl_xor(bi, off);
      if (ov > bv || (ov == bv && oi < bi)) { bv = ov; bi = oi; }
    }
    vals[t] = bv;
    idxs[t] = bi;
    if (ci == bi) cv = -1e30f;  // owner retires its candidate
  }
  float m = vals[0];
  float sum = 0.f;
#pragma unroll
  for (int t = 0; t < TK; t++) sum += expf(vals[t] - m);
  if (lane == 0) {
    const float inv = 1.f / (sum * (float)NC);
#pragma unroll
    for (int t = 0; t < TK; t++)
      atomicAdd(&W[b * SP + idxs[t]], expf(vals[t] - m) * inv);
  }
}

// ---------------- Kernel C: hpart[ch,b,d] = sum_{s in chunk} W*q ------------
__global__ __launch_bounds__(256) void h_partial(const float* __restrict__ q,
                                                 const float* __restrict__ W,
                                                 float* __restrict__ hpart) {
  const int b = blockIdx.y;
  const int ch = blockIdx.z;
  const int d = blockIdx.x * 256 + threadIdx.x;
  __shared__ float Ws[HCHS];
  if (threadIdx.x < HCHS) Ws[threadIdx.x] = W[b * SP + ch * HCHS + threadIdx.x];
  __syncthreads();
  const float* qb = q + ((size_t)b * S_TOK + 1 + ch * HCHS) * DIM + d;
  float acc = 0.f;
#pragma unroll 8
  for (int s = 0; s < HCHS; s++) acc = fmaf(Ws[s], qb[(size_t)s * DIM], acc);
  hpart[((size_t)ch * NB + b) * DIM + d] = acc;
}

// ---------------- Kernel D: y = relu(sum_ch hpart) @ cls_w^T + cls_b --------
__global__ __launch_bounds__(256) void cls_head(const float* __restrict__ hp,
                                                const float* __restrict__ cw,
                                                const float* __restrict__ cb,
                                                float* __restrict__ y) {
  __shared__ float hs[NB * DIM];
  for (int i = threadIdx.x; i < NB * DIM; i += 256) {
    float s = 0.f;
#pragma unroll
    for (int ch = 0; ch < HCH; ch++) s += hp[(size_t)ch * NB * DIM + i];
    hs[i] = fmaxf(s, 0.f);
  }
  __syncthreads();
  const int lane = threadIdx.x & 63;
  const int n = blockIdx.x * 4 + (threadIdx.x >> 6);
  float wr[12];
#pragma unroll
  for (int j = 0; j < 12; j++) wr[j] = cw[(size_t)n * DIM + lane + 64 * j];
  const float bias = cb[n];
  for (int bb = 0; bb < NB; bb++) {
    float dot = 0.f;
#pragma unroll
    for (int j = 0; j < 12; j++)
      dot = fmaf(wr[j], hs[bb * DIM + lane + 64 * j], dot);
#pragma unroll
    for (int off = 32; off >= 1; off >>= 1) dot += __shfl_xor(dot, off);
    if (lane == 0) y[bb * NCLS + n] = dot + bias;
  }
}

extern "C" void kernel_launch(void* const* d_in, const int* in_sizes, int n_in,
                              void* d_out, int out_size, void* d_ws, size_t ws_size,
                              hipStream_t stream) {
  const float* q = (const float*)d_in[0];
  const float* cw = (const float*)d_in[1];
  const float* clsw = (const float*)d_in[2];
  const float* clsb = (const float*)d_in[3];
  float* out = (float*)d_out;

  float* W = (float*)d_ws;               // NB*SP
  float* hpart = W + (size_t)NB * SP;    // HCH*NB*DIM
  float* qk = hpart + (size_t)HCH * NB * DIM;  // NB*NC*SP (37.7 MB)

  qk_gemm_bf16s<<<dim3(9, 4, NB), 256, 0, stream>>>(q, cw, qk, W);
  topk_rescore<<<(NB * NC) / 4, 256, 0, stream>>>(q, cw, qk, W);
  h_partial<<<dim3(3, NB, HCH), 256, 0, stream>>>(q, W, hpart);
  cls_head<<<NCLS / 4, 256, 0, stream>>>(hpart, clsw, clsb, out);
}

// Round 13
// 84.855 us; speedup vs baseline: 2.5769x; 1.2465x over previous
//
#include <hip/hip_runtime.h>

#define NB 16
#define S_TOK 577
#define SP 576
#define DIM 768
#define NC 256
#define NCLS 1000
#define TK 16
#define NCAND 24
#define HCH 6
#define HCHS 96  // 576/6

typedef __attribute__((ext_vector_type(8))) __bf16 bf16x8;
typedef __attribute__((ext_vector_type(4))) float f32x4;

// Read one 16B MFMA fragment (row r, k-chunk kc) from a swizzled LDS tile.
__device__ __forceinline__ bf16x8 frag_ld(const char* base, int r, int kc) {
  return *(const bf16x8*)(base + ((r * 4 + (kc ^ (r & 3))) << 4));
}

// Ordered-uint key: float-monotone high bits, (1023-s) tie-break in low 10.
__device__ __forceinline__ unsigned okey(float f, int s) {
  unsigned u = __float_as_uint(f);
  u = (u & 0x80000000u) ? ~u : (u | 0x80000000u);
  return (u & ~1023u) | (1023u - (unsigned)s);
}

// ---------------- Kernel A: qk[b,c,s] approx, single-pass bf16 MFMA --------
// 64c x 64s tile (R4/R11-validated core, hi-only). Blocks (0,0,b) zero W.
__global__ __launch_bounds__(256) void qk_gemm_bf16s(const float* __restrict__ q,
                                                     const float* __restrict__ cw,
                                                     float* __restrict__ qk,
                                                     float* __restrict__ W) {
  const int b = blockIdx.z;
  const int s0 = blockIdx.x * 64;
  const int c0 = blockIdx.y * 64;
  __shared__ __align__(16) char sAH[4096], sBH[4096];

  if (blockIdx.x == 0 && blockIdx.y == 0) {
    for (int i = threadIdx.x; i < SP; i += 256) W[b * SP + i] = 0.f;
  }

  const int tid = threadIdx.x;
  const int lane = tid & 63;
  const int wid = tid >> 6;
  const int wc = (wid >> 1) << 5;  // wave c-offset (0/32)
  const int wsv = (wid & 1) << 5;  // wave s-offset (0/32)
  const int fr = lane & 15;
  const int kq = lane >> 4;  // k-chunk 0..3

  const int r = tid >> 2;
  const int ck = tid & 3;
  const int wslot = (r * 4 + (ck ^ (r & 3))) << 4;

  const float* qb = q + ((size_t)b * S_TOK + 1) * DIM;
  const float* arow = cw + (size_t)(c0 + r) * DIM + ck * 8;
  const float* brow = qb + (size_t)(s0 + r) * DIM + ck * 8;

  f32x4 zero = {0.f, 0.f, 0.f, 0.f};
  f32x4 acc[2][2];
#pragma unroll
  for (int i = 0; i < 2; i++)
#pragma unroll
    for (int j = 0; j < 2; j++) acc[i][j] = zero;

  for (int k0 = 0; k0 < DIM; k0 += 32) {
    float4 a0 = *(const float4*)(arow + k0);
    float4 a1 = *(const float4*)(arow + k0 + 4);
    float4 b0v = *(const float4*)(brow + k0);
    float4 b1v = *(const float4*)(brow + k0 + 4);
    __syncthreads();  // previous iter's fragment readers done
    {
      float va[8] = {a0.x, a0.y, a0.z, a0.w, a1.x, a1.y, a1.z, a1.w};
      float vb[8] = {b0v.x, b0v.y, b0v.z, b0v.w, b1v.x, b1v.y, b1v.z, b1v.w};
      bf16x8 ha, hb;
#pragma unroll
      for (int i = 0; i < 8; i++) {
        ha[i] = (__bf16)va[i];
        hb[i] = (__bf16)vb[i];
      }
      *(bf16x8*)(sAH + wslot) = ha;
      *(bf16x8*)(sBH + wslot) = hb;
    }
    __syncthreads();
    bf16x8 a0h = frag_ld(sAH, wc + fr, kq);
    bf16x8 a1h = frag_ld(sAH, wc + 16 + fr, kq);
    bf16x8 b0h = frag_ld(sBH, wsv + fr, kq);
    bf16x8 b1h = frag_ld(sBH, wsv + 16 + fr, kq);
#define MF(A, B, C) C = __builtin_amdgcn_mfma_f32_16x16x32_bf16(A, B, C, 0, 0, 0)
    MF(a0h, b0h, acc[0][0]);
    MF(a0h, b1h, acc[0][1]);
    MF(a1h, b0h, acc[1][0]);
    MF(a1h, b1h, acc[1][1]);
#undef MF
  }
  // C/D layout (m89-verified): col(s) = lane&15, row(c) = (lane>>4)*4 + reg
  float* obase = qk + (size_t)b * NC * SP;
#pragma unroll
  for (int i = 0; i < 2; i++)
#pragma unroll
    for (int j = 0; j < 2; j++)
#pragma unroll
      for (int rr = 0; rr < 4; rr++) {
        const int row = c0 + wc + i * 16 + kq * 4 + rr;
        const int col = s0 + wsv + j * 16 + fr;
        obase[(size_t)row * SP + col] = acc[i][j][rr];
      }
}

// ---------------- Kernel B: top-24 approx -> exact f32 rescore -> top-16 ---
// 1024 blocks x 4 waves; wave owns one (b,c) row end-to-end.
// XCD-aware mapping: each XCD owns 2 batches -> q[b]+qk[b] (~4.7MB) stays
// L2-resident, killing the 132MB FETCH spill seen in R12.
__global__ __launch_bounds__(256) void topk_rescore(const float* __restrict__ q,
                                                    const float* __restrict__ cw,
                                                    const float* __restrict__ qk,
                                                    float* __restrict__ W) {
  __shared__ int sIdx[4][NCAND];
  __shared__ float sVal[4][NCAND];
  const int lane = threadIdx.x & 63;
  const int wid = threadIdx.x >> 6;
  const int xcd = blockIdx.x & 7;        // HW: dispatch index % 8 -> XCD
  const int slot = blockIdx.x >> 3;      // 0..127
  const int b = xcd * 2 + (slot >> 6);   // 2 batches per XCD
  const int c = (slot & 63) * 4 + wid;   // 64 blocks x 4 waves = 256 c
  const int rc = b * NC + c;

  // --- approx top-24 via packed keys (1 shfl per level) ---
  const float* rowp = qk + (size_t)rc * SP;
  unsigned k[9];
#pragma unroll
  for (int j = 0; j < 9; j++) k[j] = okey(rowp[lane + 64 * j], lane + 64 * j);

  for (int t = 0; t < NCAND; t++) {
    unsigned bk = k[0];
#pragma unroll
    for (int j = 1; j < 9; j++) bk = max(bk, k[j]);
#pragma unroll
    for (int off = 32; off >= 1; off >>= 1)
      bk = max(bk, (unsigned)__shfl_xor((int)bk, off));
    const int s = 1023 - (int)(bk & 1023u);
    const int cj = s >> 6, cl = s & 63;
#pragma unroll
    for (int j = 0; j < 9; j++)
      if (j == cj && cl == lane) k[j] = 0u;  // retire winner (static idx)
    if (lane == 0) sIdx[wid][t] = s;
  }
  __syncthreads();

  // --- exact f32 rescore of the 24 candidates ---
  const float* qrow = q + ((size_t)b * S_TOK + 1) * DIM + lane;
  const float* crow = cw + (size_t)c * DIM + lane;
  float cr[12];
#pragma unroll
  for (int m = 0; m < 12; m++) cr[m] = crow[64 * m];
  for (int t = 0; t < NCAND; t++) {
    const int s = sIdx[wid][t];
    const float* qp_ = qrow + (size_t)s * DIM;
    float d = 0.f;
#pragma unroll
    for (int m = 0; m < 12; m++) d = fmaf(qp_[64 * m], cr[m], d);
#pragma unroll
    for (int off = 32; off >= 1; off >>= 1) d += __shfl_xor(d, off);
    if (lane == 0) sVal[wid][t] = d;
  }
  __syncthreads();

  // --- exact top-16-of-24 (jax tie-break: lower s first), softmax, scatter --
  float cv = -1e30f;
  int ci = 0x7fffffff;
  if (lane < NCAND) {
    cv = sVal[wid][lane];
    ci = sIdx[wid][lane];
  }
  float vals[TK];
  int idxs[TK];
#pragma unroll
  for (int t = 0; t < TK; t++) {
    float bv = cv;
    int bi = ci;
#pragma unroll
    for (int off = 32; off >= 1; off >>= 1) {
      float ov = __shfl_xor(bv, off);
      int oi = __shfl_xor(bi, off);
      if (ov > bv || (ov == bv && oi < bi)) { bv = ov; bi = oi; }
    }
    vals[t] = bv;
    idxs[t] = bi;
    if (ci == bi) cv = -1e30f;  // owner retires its candidate
  }
  float m = vals[0];
  float sum = 0.f;
#pragma unroll
  for (int t = 0; t < TK; t++) sum += expf(vals[t] - m);
  if (lane == 0) {
    const float inv = 1.f / (sum * (float)NC);
#pragma unroll
    for (int t = 0; t < TK; t++)
      atomicAdd(&W[b * SP + idxs[t]], expf(vals[t] - m) * inv);
  }
}

// ---------------- Kernel C: hpart[ch,b,d] = sum_{s in chunk} W*q ------------
__global__ __launch_bounds__(256) void h_partial(const float* __restrict__ q,
                                                 const float* __restrict__ W,
                                                 float* __restrict__ hpart) {
  const int b = blockIdx.y;
  const int ch = blockIdx.z;
  const int d = blockIdx.x * 256 + threadIdx.x;
  __shared__ float Ws[HCHS];
  if (threadIdx.x < HCHS) Ws[threadIdx.x] = W[b * SP + ch * HCHS + threadIdx.x];
  __syncthreads();
  const float* qb = q + ((size_t)b * S_TOK + 1 + ch * HCHS) * DIM + d;
  float acc = 0.f;
#pragma unroll 8
  for (int s = 0; s < HCHS; s++) acc = fmaf(Ws[s], qb[(size_t)s * DIM], acc);
  hpart[((size_t)ch * NB + b) * DIM + d] = acc;
}

// ---------------- Kernel D: y = relu(sum_ch hpart) @ cls_w^T + cls_b --------
__global__ __launch_bounds__(256) void cls_head(const float* __restrict__ hp,
                                                const float* __restrict__ cw,
                                                const float* __restrict__ cb,
                                                float* __restrict__ y) {
  __shared__ float hs[NB * DIM];
  for (int i = threadIdx.x; i < NB * DIM; i += 256) {
    float s = 0.f;
#pragma unroll
    for (int ch = 0; ch < HCH; ch++) s += hp[(size_t)ch * NB * DIM + i];
    hs[i] = fmaxf(s, 0.f);
  }
  __syncthreads();
  const int lane = threadIdx.x & 63;
  const int n = blockIdx.x * 4 + (threadIdx.x >> 6);
  float wr[12];
#pragma unroll
  for (int j = 0; j < 12; j++) wr[j] = cw[(size_t)n * DIM + lane + 64 * j];
  const float bias = cb[n];
  for (int bb = 0; bb < NB; bb++) {
    float dot = 0.f;
#pragma unroll
    for (int j = 0; j < 12; j++)
      dot = fmaf(wr[j], hs[bb * DIM + lane + 64 * j], dot);
#pragma unroll
    for (int off = 32; off >= 1; off >>= 1) dot += __shfl_xor(dot, off);
    if (lane == 0) y[bb * NCLS + n] = dot + bias;
  }
}

extern "C" void kernel_launch(void* const* d_in, const int* in_sizes, int n_in,
                              void* d_out, int out_size, void* d_ws, size_t ws_size,
                              hipStream_t stream) {
  const float* q = (const float*)d_in[0];
  const float* cw = (const float*)d_in[1];
  const float* clsw = (const float*)d_in[2];
  const float* clsb = (const float*)d_in[3];
  float* out = (float*)d_out;

  float* W = (float*)d_ws;               // NB*SP
  float* hpart = W + (size_t)NB * SP;    // HCH*NB*DIM
  float* qk = hpart + (size_t)HCH * NB * DIM;  // NB*NC*SP (9.4 MB)

  qk_gemm_bf16s<<<dim3(9, 4, NB), 256, 0, stream>>>(q, cw, qk, W);
  topk_rescore<<<(NB * NC) / 4, 256, 0, stream>>>(q, cw, qk, W);
  h_partial<<<dim3(3, NB, HCH), 256, 0, stream>>>(q, W, hpart);
  cls_head<<<NCLS / 4, 256, 0, stream>>>(hpart, clsw, clsb, out);
}